// Round 1
// baseline (196.155 us; speedup 1.0000x reference)
//
#include <hip/hip_runtime.h>
#include <hip/hip_bf16.h>
#include <stdint.h>

#define B_SZ 1024
#define N_SZ 65536
#define M_SZ 128

typedef short bf16x8 __attribute__((ext_vector_type(8)));
typedef float f32x4 __attribute__((ext_vector_type(4)));

__device__ __forceinline__ unsigned short f2bf(float f) {
    uint32_t u = __float_as_uint(f);
    uint32_t r = (u + 0x7FFFu + ((u >> 16) & 1u)) >> 16;  // RNE
    return (unsigned short)r;
}

// ---- kernel 0: EDt[c][b] bf16, c<128 -> E[b][c], else D[b][c-128]. [256][1024]
__global__ __launch_bounds__(256) void k_edt(const float* __restrict__ E,
                                             const float* __restrict__ D,
                                             unsigned short* __restrict__ EDt) {
    __shared__ float tile[32][33];
    int bx = blockIdx.x & 31;
    int cy = blockIdx.x >> 5;
    int b0 = bx * 32, c0 = cy * 32;
    const float* src = (c0 < M_SZ) ? E : D;
    int cs0 = c0 & (M_SZ - 1);
    int t = threadIdx.x;
    int i = t >> 3, j = (t & 7) * 4;
    const float* p = src + (size_t)(b0 + i) * M_SZ + cs0 + j;
    float4 v = *(const float4*)p;
    tile[i][j] = v.x; tile[i][j + 1] = v.y; tile[i][j + 2] = v.z; tile[i][j + 3] = v.w;
    __syncthreads();
    int c = t >> 3, b4 = (t & 7) * 4;
    unsigned short* q = EDt + (size_t)(c0 + c) * B_SZ + b0 + b4;
    ushort4 o;
    o.x = f2bf(tile[b4 + 0][c]); o.y = f2bf(tile[b4 + 1][c]);
    o.z = f2bf(tile[b4 + 2][c]); o.w = f2bf(tile[b4 + 3][c]);
    *(ushort4*)q = o;
}

// ---- zero d_out (atomics accumulate into it)
__global__ __launch_bounds__(256) void k_zero(float* __restrict__ out) {
    int i = blockIdx.x * 1024 + threadIdx.x * 4;
    *(float4*)(out + i) = (float4){0.f, 0.f, 0.f, 0.f};
}

// ---- pass 1: NC[n][m] = C[n][m]*(1-W) + V,  W|V = A^T @ (E||D)
#define AS_LD 132   // [32 kb][132] pad: stride 66 dwords -> scalar frag reads 2-way (free)
#define ED_LD 40    // [256 col][40] pad: 80B rows, 16B aligned b128 reads

__global__ __launch_bounds__(256, 2) void k_pass1(
    const float* __restrict__ A,            // [B][N]
    const unsigned short* __restrict__ EDt, // [256][B] bf16
    const float* __restrict__ C,            // [N][M]
    unsigned short* __restrict__ NC)        // [N][M] bf16 out
{
    __shared__ __align__(16) unsigned short As[32 * AS_LD];
    __shared__ __align__(16) unsigned short EDs[256 * ED_LD];
    const int t = threadIdx.x;
    const int lane = t & 63;
    const int wv = t >> 6;
    const int g = lane >> 4;
    const int m16 = lane & 15;
    const int n0 = blockIdx.x * 128;

    f32x4 acc[2][16];
#pragma unroll
    for (int i = 0; i < 2; ++i)
#pragma unroll
        for (int j = 0; j < 16; ++j)
            acc[i][j] = (f32x4){0.f, 0.f, 0.f, 0.f};

    const int kb = t >> 3;          // staging row 0..31 (b-dim)
    const int cA = (t & 7) * 16;    // staging col
    const int colq = t >> 3;        // EDs staging
    const int seg = t & 7;

    for (int bk0 = 0; bk0 < B_SZ; bk0 += 32) {
        __syncthreads();
        {   // stage A[bk0..+32][n0..+128] -> As[kb][n] bf16 (transposed-use tile)
            const float* p = A + (size_t)(bk0 + kb) * N_SZ + n0 + cA;
            float4 v0 = *(const float4*)(p + 0);
            float4 v1 = *(const float4*)(p + 4);
            float4 v2 = *(const float4*)(p + 8);
            float4 v3 = *(const float4*)(p + 12);
            ushort4* w = (ushort4*)&As[kb * AS_LD + cA];
            ushort4 o;
            o.x = f2bf(v0.x); o.y = f2bf(v0.y); o.z = f2bf(v0.z); o.w = f2bf(v0.w); w[0] = o;
            o.x = f2bf(v1.x); o.y = f2bf(v1.y); o.z = f2bf(v1.z); o.w = f2bf(v1.w); w[1] = o;
            o.x = f2bf(v2.x); o.y = f2bf(v2.y); o.z = f2bf(v2.z); o.w = f2bf(v2.w); w[2] = o;
            o.x = f2bf(v3.x); o.y = f2bf(v3.y); o.z = f2bf(v3.z); o.w = f2bf(v3.w); w[3] = o;
        }
#pragma unroll
        for (int p8 = 0; p8 < 8; ++p8) {  // stage EDt[col][bk0..+32] -> EDs[col][k]
            int col = p8 * 32 + colq;
            ushort4 v = *(const ushort4*)(EDt + (size_t)col * B_SZ + bk0 + seg * 4);
            *(ushort4*)&EDs[col * ED_LD + seg * 4] = v;
        }
        __syncthreads();

        bf16x8 af[2];
#pragma unroll
        for (int fi = 0; fi < 2; ++fi) {   // A-operand: row n = l&15(+16fi), k contiguous
            int nl = wv * 32 + fi * 16 + m16;
#pragma unroll
            for (int j = 0; j < 8; ++j)
                af[fi][j] = (short)As[(g * 8 + j) * AS_LD + nl];
        }
#pragma unroll
        for (int fj = 0; fj < 16; ++fj) {  // B-operand: col = l&15, k contiguous
            bf16x8 bfr = *(const bf16x8*)&EDs[(fj * 16 + m16) * ED_LD + g * 8];
            acc[0][fj] = __builtin_amdgcn_mfma_f32_16x16x32_bf16(af[0], bfr, acc[0][fj], 0, 0, 0);
            acc[1][fj] = __builtin_amdgcn_mfma_f32_16x16x32_bf16(af[1], bfr, acc[1][fj], 0, 0, 0);
        }
    }

    // epilogue: D layout col=lane&15, row=(lane>>4)*4+r  (m89-verified)
#pragma unroll
    for (int fi = 0; fi < 2; ++fi)
#pragma unroll
        for (int fj = 0; fj < 8; ++fj)
#pragma unroll
            for (int r = 0; r < 4; ++r) {
                int n = n0 + wv * 32 + fi * 16 + g * 4 + r;
                int m = fj * 16 + m16;
                float w = acc[fi][fj][r];       // erase_v
                float v = acc[fi][fj + 8][r];   // add_v
                float cc = C[(size_t)n * M_SZ + m];
                NC[(size_t)n * M_SZ + m] = f2bf(cc * (1.0f - w) + v);
            }
}

// ---- pass 2: out[b][m] += A[b][k]*NC[k][m], K split 64-way, atomics
#define A2_LD 40
#define NC_LD 132

__global__ __launch_bounds__(256, 2) void k_pass2(
    const float* __restrict__ A,
    const unsigned short* __restrict__ NC,
    float* __restrict__ out)
{
    __shared__ __align__(16) unsigned short As[128 * A2_LD];
    __shared__ __align__(16) unsigned short NCs[32 * NC_LD];
    const int t = threadIdx.x;
    const int lane = t & 63;
    const int wv = t >> 6;
    const int g = lane >> 4;
    const int m16 = lane & 15;
    const int b0 = (blockIdx.x & 7) * 128;
    const int k0 = (blockIdx.x >> 3) * 1024;

    f32x4 acc[8][2];
#pragma unroll
    for (int i = 0; i < 8; ++i) {
        acc[i][0] = (f32x4){0.f, 0.f, 0.f, 0.f};
        acc[i][1] = (f32x4){0.f, 0.f, 0.f, 0.f};
    }

    const int bA = t >> 1, half = t & 1;
    const int kr = t >> 3, cN = (t & 7) * 16;

    for (int kk = 0; kk < 1024; kk += 32) {
        const int kbase = k0 + kk;
        __syncthreads();
        {   // stage A[b0..+128][kbase..+32] -> As[b][k]
            const float* p = A + (size_t)(b0 + bA) * N_SZ + kbase + half * 16;
            float4 v0 = *(const float4*)(p + 0);
            float4 v1 = *(const float4*)(p + 4);
            float4 v2 = *(const float4*)(p + 8);
            float4 v3 = *(const float4*)(p + 12);
            ushort4* w = (ushort4*)&As[bA * A2_LD + half * 16];
            ushort4 o;
            o.x = f2bf(v0.x); o.y = f2bf(v0.y); o.z = f2bf(v0.z); o.w = f2bf(v0.w); w[0] = o;
            o.x = f2bf(v1.x); o.y = f2bf(v1.y); o.z = f2bf(v1.z); o.w = f2bf(v1.w); w[1] = o;
            o.x = f2bf(v2.x); o.y = f2bf(v2.y); o.z = f2bf(v2.z); o.w = f2bf(v2.w); w[2] = o;
            o.x = f2bf(v3.x); o.y = f2bf(v3.y); o.z = f2bf(v3.z); o.w = f2bf(v3.w); w[3] = o;
        }
        {   // stage NC[kbase..+32][:] -> NCs[k][m]
            const ushort4* p = (const ushort4*)(NC + (size_t)(kbase + kr) * M_SZ + cN);
            ushort4 v0 = p[0], v1 = p[1], v2 = p[2], v3 = p[3];
            ushort4* w = (ushort4*)&NCs[kr * NC_LD + cN];
            w[0] = v0; w[1] = v1; w[2] = v2; w[3] = v3;
        }
        __syncthreads();

        bf16x8 bfr[2];
#pragma unroll
        for (int fj = 0; fj < 2; ++fj) {   // B-operand transpose reads (pad 132 -> 2-way, free)
            int m = wv * 32 + fj * 16 + m16;
#pragma unroll
            for (int j = 0; j < 8; ++j)
                bfr[fj][j] = (short)NCs[(g * 8 + j) * NC_LD + m];
        }
#pragma unroll
        for (int fi = 0; fi < 8; ++fi) {
            bf16x8 afr = *(const bf16x8*)&As[(fi * 16 + m16) * A2_LD + g * 8];
            acc[fi][0] = __builtin_amdgcn_mfma_f32_16x16x32_bf16(afr, bfr[0], acc[fi][0], 0, 0, 0);
            acc[fi][1] = __builtin_amdgcn_mfma_f32_16x16x32_bf16(afr, bfr[1], acc[fi][1], 0, 0, 0);
        }
    }

#pragma unroll
    for (int fi = 0; fi < 8; ++fi)
#pragma unroll
        for (int fj = 0; fj < 2; ++fj)
#pragma unroll
            for (int r = 0; r < 4; ++r) {
                int b = b0 + fi * 16 + g * 4 + r;
                int m = wv * 32 + fj * 16 + m16;
                atomicAdd(out + (size_t)b * M_SZ + m, acc[fi][fj][r]);
            }
}

extern "C" void kernel_launch(void* const* d_in, const int* in_sizes, int n_in,
                              void* d_out, int out_size, void* d_ws, size_t ws_size,
                              hipStream_t stream) {
    const float* A  = (const float*)d_in[0];   // address [B,N]
    const float* E  = (const float*)d_in[1];   // erase   [B,M]
    const float* Dd = (const float*)d_in[2];   // add     [B,M]
    const float* C  = (const float*)d_in[3];   // content [N,M]
    float* out = (float*)d_out;

    unsigned short* NC  = (unsigned short*)d_ws;                              // 16 MB
    unsigned short* EDt = (unsigned short*)((char*)d_ws + (size_t)N_SZ * M_SZ * 2);  // +512 KB

    k_edt <<<256, 256, 0, stream>>>(E, Dd, EDt);
    k_zero<<<128, 256, 0, stream>>>(out);
    k_pass1<<<512, 256, 0, stream>>>(A, EDt, C, NC);
    k_pass2<<<512, 256, 0, stream>>>(A, NC, out);
}

// Round 3
// 175.759 us; speedup vs baseline: 1.1160x; 1.1160x over previous
//
#include <hip/hip_runtime.h>
#include <hip/hip_bf16.h>
#include <stdint.h>

#define B_SZ 1024
#define N_SZ 65536
#define M_SZ 128

typedef short bf16x8 __attribute__((ext_vector_type(8)));
typedef short bf16x4 __attribute__((ext_vector_type(4)));
typedef float f32x4 __attribute__((ext_vector_type(4)));

__device__ __forceinline__ unsigned short f2bf(float f) {
    uint32_t u = __float_as_uint(f);
    uint32_t r = (u + 0x7FFFu + ((u >> 16) & 1u)) >> 16;  // RNE
    return (unsigned short)r;
}

// ---- kernel 0: EDt[c][b] bf16, c<128 -> E[b][c], else D[b][c-128]. [256][1024]
__global__ __launch_bounds__(256) void k_edt(const float* __restrict__ E,
                                             const float* __restrict__ D,
                                             unsigned short* __restrict__ EDt) {
    __shared__ float tile[32][33];
    int bx = blockIdx.x & 31;
    int cy = blockIdx.x >> 5;
    int b0 = bx * 32, c0 = cy * 32;
    const float* src = (c0 < M_SZ) ? E : D;
    int cs0 = c0 & (M_SZ - 1);
    int t = threadIdx.x;
    int i = t >> 3, j = (t & 7) * 4;
    const float* p = src + (size_t)(b0 + i) * M_SZ + cs0 + j;
    float4 v = *(const float4*)p;
    tile[i][j] = v.x; tile[i][j + 1] = v.y; tile[i][j + 2] = v.z; tile[i][j + 3] = v.w;
    __syncthreads();
    int c = t >> 3, b4 = (t & 7) * 4;
    unsigned short* q = EDt + (size_t)(c0 + c) * B_SZ + b0 + b4;
    ushort4 o;
    o.x = f2bf(tile[b4 + 0][c]); o.y = f2bf(tile[b4 + 1][c]);
    o.z = f2bf(tile[b4 + 2][c]); o.w = f2bf(tile[b4 + 3][c]);
    *(ushort4*)q = o;
}

__global__ __launch_bounds__(256) void k_zero(float* __restrict__ out) {
    int i = blockIdx.x * 1024 + threadIdx.x * 4;
    *(float4*)(out + i) = (float4){0.f, 0.f, 0.f, 0.f};
}

// =======================  PASS 1  =======================
// NCt[m][n] = C[n][m]*(1-W[n][m]) + V[n][m],  (W|V) = A^T @ (E||D)
// block: 128 n x 256 c, K=1024 in 32-chunks, double-buffered reg-staged.
// waves 2x2 (wvn,wvc): wave tile 64n x (64 W-cols + 64 V-cols paired).
// As: [32 k][132] bf16 (pad-132: scalar frag reads 2-way alias = free).
// EDs: [256 c][40] bf16, k-contiguous rows.
#define AS_LD 132
#define ED_LD 40

__global__ __launch_bounds__(256, 2) void k_pass1(
    const float* __restrict__ A,            // [B][N]
    const unsigned short* __restrict__ EDt, // [256][B] bf16
    const float* __restrict__ C,            // [N][M]
    unsigned short* __restrict__ NCt)       // [M][N] bf16 out (transposed!)
{
    __shared__ __align__(16) unsigned short As[2][32 * AS_LD];
    __shared__ __align__(16) unsigned short EDs[2][256 * ED_LD];
    const int t = threadIdx.x;
    const int lane = t & 63;
    const int wv = t >> 6;
    const int wvn = wv >> 1, wvc = wv & 1;
    const int g = lane >> 4;
    const int m16 = lane & 15;
    const int n0 = blockIdx.x * 128;

    // staging roles (R1-proven mappings)
    const int kb = t >> 3;          // A: b-row within chunk 0..31
    const int cA = (t & 7) * 16;    // A: n-col start
    const int colq = t >> 3;        // ED: col 0..31 (+32*p8)
    const int seg = t & 7;          // ED: 4-short segment

    int cb[8];
#pragma unroll
    for (int fj = 0; fj < 4; ++fj) { cb[fj] = wvc * 4 + fj; cb[fj + 4] = 8 + wvc * 4 + fj; }

    f32x4 acc[4][8];
#pragma unroll
    for (int i = 0; i < 4; ++i)
#pragma unroll
        for (int j = 0; j < 8; ++j) acc[i][j] = (f32x4){0.f, 0.f, 0.f, 0.f};

    // ---- prologue: stage chunk 0 into buf 0
    {
        const float* p = A + (size_t)kb * N_SZ + n0 + cA;
        float4 a0 = ((const float4*)p)[0], a1 = ((const float4*)p)[1];
        float4 a2 = ((const float4*)p)[2], a3 = ((const float4*)p)[3];
        ushort4* w = (ushort4*)&As[0][kb * AS_LD + cA];
        ushort4 o;
        o.x = f2bf(a0.x); o.y = f2bf(a0.y); o.z = f2bf(a0.z); o.w = f2bf(a0.w); w[0] = o;
        o.x = f2bf(a1.x); o.y = f2bf(a1.y); o.z = f2bf(a1.z); o.w = f2bf(a1.w); w[1] = o;
        o.x = f2bf(a2.x); o.y = f2bf(a2.y); o.z = f2bf(a2.z); o.w = f2bf(a2.w); w[2] = o;
        o.x = f2bf(a3.x); o.y = f2bf(a3.y); o.z = f2bf(a3.z); o.w = f2bf(a3.w); w[3] = o;
#pragma unroll
        for (int p8 = 0; p8 < 8; ++p8) {
            int col = p8 * 32 + colq;
            ushort4 v = *(const ushort4*)(EDt + (size_t)col * B_SZ + seg * 4);
            *(ushort4*)&EDs[0][col * ED_LD + seg * 4] = v;
        }
    }
    __syncthreads();

    int cur = 0;
    for (int bk = 0; bk < B_SZ; bk += 32) {
        const bool last = (bk + 32 >= B_SZ);
        const int nk = last ? 0 : bk + 32;

        // (1) prefetch next chunk -> regs
        const float* p = A + (size_t)(nk + kb) * N_SZ + n0 + cA;
        float4 a0 = ((const float4*)p)[0], a1 = ((const float4*)p)[1];
        float4 a2 = ((const float4*)p)[2], a3 = ((const float4*)p)[3];
        ushort4 e[8];
#pragma unroll
        for (int p8 = 0; p8 < 8; ++p8) {
            int col = p8 * 32 + colq;
            e[p8] = *(const ushort4*)(EDt + (size_t)col * B_SZ + nk + seg * 4);
        }

        // (2) fragment reads from buf[cur]
        bf16x8 af[4];
#pragma unroll
        for (int fi = 0; fi < 4; ++fi) {
            int nl = wvn * 64 + fi * 16 + m16;
#pragma unroll
            for (int j = 0; j < 8; ++j)
                af[fi][j] = (short)As[cur][(g * 8 + j) * AS_LD + nl];
        }
        bf16x8 bfr[8];
#pragma unroll
        for (int fj = 0; fj < 8; ++fj)
            bfr[fj] = *(const bf16x8*)&EDs[cur][(cb[fj] * 16 + m16) * ED_LD + g * 8];

        // (3) MFMAs
#pragma unroll
        for (int fj = 0; fj < 8; ++fj)
#pragma unroll
            for (int fi = 0; fi < 4; ++fi)
                acc[fi][fj] = __builtin_amdgcn_mfma_f32_16x16x32_bf16(af[fi], bfr[fj], acc[fi][fj], 0, 0, 0);

        // (4) convert + write next buffer
        if (!last) {
            const int nxt = cur ^ 1;
            ushort4* w = (ushort4*)&As[nxt][kb * AS_LD + cA];
            ushort4 o;
            o.x = f2bf(a0.x); o.y = f2bf(a0.y); o.z = f2bf(a0.z); o.w = f2bf(a0.w); w[0] = o;
            o.x = f2bf(a1.x); o.y = f2bf(a1.y); o.z = f2bf(a1.z); o.w = f2bf(a1.w); w[1] = o;
            o.x = f2bf(a2.x); o.y = f2bf(a2.y); o.z = f2bf(a2.z); o.w = f2bf(a2.w); w[2] = o;
            o.x = f2bf(a3.x); o.y = f2bf(a3.y); o.z = f2bf(a3.z); o.w = f2bf(a3.w); w[3] = o;
#pragma unroll
            for (int p8 = 0; p8 < 8; ++p8) {
                int col = p8 * 32 + colq;
                *(ushort4*)&EDs[nxt][col * ED_LD + seg * 4] = e[p8];
            }
        }
        __syncthreads();
        cur ^= 1;
    }

    // epilogue: D layout col=lane&15, row=(lane>>4)*4+r (m89-verified).
    // Write NCt[m][n]: per lane, n = n_base + r is CONTIGUOUS -> bf16x4 store.
#pragma unroll
    for (int fi = 0; fi < 4; ++fi)
#pragma unroll
        for (int fj = 0; fj < 4; ++fj) {
            int n_base = n0 + wvn * 64 + fi * 16 + g * 4;
            int m = wvc * 64 + fj * 16 + m16;
            bf16x4 o;
#pragma unroll
            for (int r = 0; r < 4; ++r) {
                float w = acc[fi][fj][r];       // erase_v
                float v = acc[fi][fj + 4][r];   // add_v
                float cc = C[(size_t)(n_base + r) * M_SZ + m];
                o[r] = (short)f2bf(cc * (1.0f - w) + v);
            }
            *(bf16x4*)&NCt[(size_t)m * N_SZ + n_base] = o;
        }
}

// =======================  PASS 2  =======================
// out[b][m] += A[b][k] * NCt[m][k]; block = 128b x 128m, K-split 64 x 1024.
// Both operands contraction-innermost -> fully linear LDS. Double-buffered.
#define L2_LD 40

__global__ __launch_bounds__(256, 2) void k_pass2(
    const float* __restrict__ A,
    const unsigned short* __restrict__ NCt,  // [M][N]
    float* __restrict__ out)
{
    __shared__ __align__(16) unsigned short As2[2][128 * L2_LD];
    __shared__ __align__(16) unsigned short NCs[2][128 * L2_LD];
    const int t = threadIdx.x;
    const int lane = t & 63;
    const int wv = t >> 6;
    const int wvb = wv >> 1, wvm = wv & 1;
    const int g = lane >> 4;
    const int m16 = lane & 15;
    const int b0 = (blockIdx.x & 7) * 128;
    const int k0 = (blockIdx.x >> 3) * 1024;

    const int row = t >> 1, half = t & 1;  // staging: row 0..127, 16-k half

    f32x4 acc[4][4];
#pragma unroll
    for (int i = 0; i < 4; ++i)
#pragma unroll
        for (int j = 0; j < 4; ++j) acc[i][j] = (f32x4){0.f, 0.f, 0.f, 0.f};

    // prologue: stage chunk 0 -> buf 0
    {
        const float* p = A + (size_t)(b0 + row) * N_SZ + k0 + half * 16;
        float4 a0 = ((const float4*)p)[0], a1 = ((const float4*)p)[1];
        float4 a2 = ((const float4*)p)[2], a3 = ((const float4*)p)[3];
        ushort4* w = (ushort4*)&As2[0][row * L2_LD + half * 16];
        ushort4 o;
        o.x = f2bf(a0.x); o.y = f2bf(a0.y); o.z = f2bf(a0.z); o.w = f2bf(a0.w); w[0] = o;
        o.x = f2bf(a1.x); o.y = f2bf(a1.y); o.z = f2bf(a1.z); o.w = f2bf(a1.w); w[1] = o;
        o.x = f2bf(a2.x); o.y = f2bf(a2.y); o.z = f2bf(a2.z); o.w = f2bf(a2.w); w[2] = o;
        o.x = f2bf(a3.x); o.y = f2bf(a3.y); o.z = f2bf(a3.z); o.w = f2bf(a3.w); w[3] = o;
        const uint4* pn = (const uint4*)(NCt + (size_t)row * N_SZ + k0 + half * 16);
        uint4 n0v = pn[0], n1v = pn[1];
        uint4* wn = (uint4*)&NCs[0][row * L2_LD + half * 16];
        wn[0] = n0v; wn[1] = n1v;
    }
    __syncthreads();

    int cur = 0;
    for (int kk = 0; kk < 1024; kk += 32) {
        const bool last = (kk + 32 >= 1024);
        const int nkk = last ? 0 : kk + 32;

        // prefetch
        const float* p = A + (size_t)(b0 + row) * N_SZ + k0 + nkk + half * 16;
        float4 a0 = ((const float4*)p)[0], a1 = ((const float4*)p)[1];
        float4 a2 = ((const float4*)p)[2], a3 = ((const float4*)p)[3];
        const uint4* pn = (const uint4*)(NCt + (size_t)row * N_SZ + k0 + nkk + half * 16);
        uint4 n0v = pn[0], n1v = pn[1];

        // fragment reads (all linear b128)
        bf16x8 af[4];
#pragma unroll
        for (int fi = 0; fi < 4; ++fi)
            af[fi] = *(const bf16x8*)&As2[cur][(wvb * 64 + fi * 16 + m16) * L2_LD + g * 8];
        bf16x8 bfr[4];
#pragma unroll
        for (int fj = 0; fj < 4; ++fj)
            bfr[fj] = *(const bf16x8*)&NCs[cur][(wvm * 64 + fj * 16 + m16) * L2_LD + g * 8];

#pragma unroll
        for (int fi = 0; fi < 4; ++fi)
#pragma unroll
            for (int fj = 0; fj < 4; ++fj)
                acc[fi][fj] = __builtin_amdgcn_mfma_f32_16x16x32_bf16(af[fi], bfr[fj], acc[fi][fj], 0, 0, 0);

        if (!last) {
            const int nxt = cur ^ 1;
            ushort4* w = (ushort4*)&As2[nxt][row * L2_LD + half * 16];
            ushort4 o;
            o.x = f2bf(a0.x); o.y = f2bf(a0.y); o.z = f2bf(a0.z); o.w = f2bf(a0.w); w[0] = o;
            o.x = f2bf(a1.x); o.y = f2bf(a1.y); o.z = f2bf(a1.z); o.w = f2bf(a1.w); w[1] = o;
            o.x = f2bf(a2.x); o.y = f2bf(a2.y); o.z = f2bf(a2.z); o.w = f2bf(a2.w); w[2] = o;
            o.x = f2bf(a3.x); o.y = f2bf(a3.y); o.z = f2bf(a3.z); o.w = f2bf(a3.w); w[3] = o;
            uint4* wn = (uint4*)&NCs[nxt][row * L2_LD + half * 16];
            wn[0] = n0v; wn[1] = n1v;
        }
        __syncthreads();
        cur ^= 1;
    }

#pragma unroll
    for (int fi = 0; fi < 4; ++fi)
#pragma unroll
        for (int fj = 0; fj < 4; ++fj)
#pragma unroll
            for (int r = 0; r < 4; ++r) {
                int b = b0 + wvb * 64 + fi * 16 + g * 4 + r;
                int m = wvm * 64 + fj * 16 + m16;
                atomicAdd(out + (size_t)b * M_SZ + m, acc[fi][fj][r]);
            }
}

extern "C" void kernel_launch(void* const* d_in, const int* in_sizes, int n_in,
                              void* d_out, int out_size, void* d_ws, size_t ws_size,
                              hipStream_t stream) {
    const float* A  = (const float*)d_in[0];   // address [B,N]
    const float* E  = (const float*)d_in[1];   // erase   [B,M]
    const float* Dd = (const float*)d_in[2];   // add     [B,M]
    const float* C  = (const float*)d_in[3];   // content [N,M]
    float* out = (float*)d_out;

    unsigned short* NCt = (unsigned short*)d_ws;                                     // 16 MB [M][N]
    unsigned short* EDt = (unsigned short*)((char*)d_ws + (size_t)M_SZ * N_SZ * 2);  // +512 KB

    k_edt <<<256, 256, 0, stream>>>(E, Dd, EDt);
    k_zero<<<128, 256, 0, stream>>>(out);
    k_pass1<<<512, 256, 0, stream>>>(A, EDt, C, NCt);
    k_pass2<<<512, 256, 0, stream>>>(A, NCt, out);
}